// Round 6
// baseline (312.028 us; speedup 1.0000x reference)
//
#include <hip/hip_runtime.h>

typedef __attribute__((ext_vector_type(8))) short short8;
typedef __attribute__((ext_vector_type(4))) float float4v;

#define NLAGS 9
#define HID 256
#define GSAMP 16
#define MROWS 144          // 9 lag-tiles of 16 samples (LAG-MAJOR: row = lag*16 + samp)
#define NTHREADS 512
// SINGLE tile buffer (sL then sW, sequential reuse): 9 tiles * 4096 shorts
// + 256 shorts (512B f32 scratch) = 74,240 B -> 2 blocks/CU possible
#define SBUF_SHORTS (36864 + 256)

union S8 { short8 v; unsigned short u[8]; };

__device__ __forceinline__ unsigned short f2b(float f) {
  union { float f; unsigned int i; } c; c.f = f;
  return (unsigned short)((c.i + 0x7FFFu + ((c.i >> 16) & 1u)) >> 16);  // RNE
}
__device__ __forceinline__ float sane(float x) {
  return (__builtin_isfinite(x) && fabsf(x) < 1e30f) ? x : 0.0f;
}
// HW packed f32->bf16 (RNE), 1 VALU op for 2 conversions
__device__ __forceinline__ unsigned int pkbf16(float lo, float hi) {
  unsigned int r;
  asm("v_cvt_pk_bf16_f32 %0, %1, %2" : "=v"(r) : "v"(lo), "v"(hi));
  return r;
}
// unclamped tanh: exp->0 gives -1, exp->inf gives +1; finite-in => finite-out
// BLACKLIST (r8-r10 bisect): bias-init-in-MFMA-C and exp2f-tanh broke correctness.
// REGISTER MODEL (R1-R5, all six rounds consistent):
//   Compiler budgets SPLIT 256-reg files: ARCH CAP = 256/min_waves
//     ((512,2)->128; (512,3)->84; (512,4)->64). Demand>cap => scratch spill.
//   HW occupancy uses TOTAL = arch + agpr vs UNIFIED 512 file:
//     waves/SIMD = floor(512/total); 8-wave blocks => 2 blocks/CU iff total<=128.
//   R5 lesson: full unroll of the mg loop let CSE hoist group-invariant
//   B-fragment loads -> arch 104->116 -> total 140 -> still 1 block.
//   Fix: #pragma unroll 1 + per-iteration opaque offset (asm "+v") so B-loads
//   can't be hoisted; Phase A split to two 4-col passes (params 32->16 regs).
__device__ __forceinline__ float ftanh(float x) {
  float t = __expf(2.0f * x);
  return 1.0f - 2.0f * __builtin_amdgcn_rcpf(t + 1.0f);
}
__device__ __forceinline__ float4v mfma16(short8 a, short8 b, float4v c) {
  return __builtin_amdgcn_mfma_f32_16x16x32_bf16(a, b, c, 0, 0, 0);
}

// ---- tile-major bf16 LDS layout: [tile m][kk-block of 32 cols][row 0..15][col&31]
// XOR bank swizzle: rotate the 32B sub-chunk (short bits 4-5) by ((col>>5)^(row>>2))&3.
//  * gemm ds_read_b128: bijection within each 1KB block => conflict-free.
//  * Phase-B b16 stores: 8-way conflict -> <=2-way (free).
//  * Phase-A b64 stores: spread across bank groups.
__device__ __forceinline__ int tmC(int row, int c) {        // chunk c = col/8, 0..31
  int base = ((row >> 4) * 8 + (c >> 2)) * 512 + (row & 15) * 32 + (c & 3) * 8;
  return base ^ ((((c >> 2) ^ (row >> 2)) & 3) << 4);
}
__device__ __forceinline__ int tmE(int row, int col) {      // single element
  int base = ((row >> 4) * 8 + (col >> 5)) * 512 + (row & 15) * 32 + (col & 31);
  return base ^ ((((col >> 5) ^ (row >> 2)) & 3) << 4);
}

#define A_TABLE { \
    {0,0,0,0,0,0,0,0,1}, \
    {1,0,0,0,0,0,0,0,0}, \
    {1.f/3,2.f/3,0,0,0,0,0,0,0}, \
    {0.2f,0.4f,0.4f,0,0,0,0,0,0}, \
    {0,0.2f,0.4f,0.4f,0,0,0,0,0}, \
    {0,0,0.2f,0.4f,0.4f,0,0,0,0}, \
    {0,0,0,0.2f,0.4f,0.4f,0,0,0}, \
    {0,0,0,0,0.25f,0.5f,0.25f,0,0}, \
    {0,0,0,0,0,1.f/3,1.f/3,1.f/3,0}, \
  }

// ---- prep_all: (blocks 0..271) f32 weights -> transposed bf16 ws tables;
//      (blocks 272..848) prep2a wave-per-output: V1/V2'/C0 -> vtab staging.
// ws (bf16): Wl2t[256][256] @0, Ww2t @65536, Ww1p[256][32] @131072 (K pad 8->32)
// vtab staging (f32): V1 @5120 [9][256], V2' @7424 [9][256], C0 @9728
__global__ void prep_all(const float* __restrict__ Wl2,
                         const float* __restrict__ Ww2,
                         const float* __restrict__ Ww1,
                         const float* __restrict__ Wm2,
                         const float* __restrict__ Wreg,
                         const float* __restrict__ bm2,
                         const float* __restrict__ breg,
                         unsigned short* __restrict__ ws,
                         float* __restrict__ vtab)
{
  const int b = blockIdx.x;
  if (b < 272) {
    int idx = b * 512 + threadIdx.x;   // 0..139263
    if (idx < 65536) {
      int n = idx >> 8, k = idx & 255;
      ws[idx] = f2b(sane(Wl2[k * 256 + n]));
    } else if (idx < 131072) {
      int j = idx - 65536; int n = j >> 8, k = j & 255;
      ws[idx] = f2b(sane(Ww2[k * 256 + n]));
    } else if (idx < 139264) {
      int j = idx - 131072; int n = j >> 5, k = j & 31;
      ws[idx] = (k < 8) ? f2b(sane(Ww1[k * 256 + n])) : (unsigned short)0;
    }
    return;
  }
  // ---- prep2a: one wave per output element ----
  const float A[9][9] = A_TABLE;
  const int lane = threadIdx.x & 63;
  const int g = (b - 272) * 8 + (threadIdx.x >> 6);
  if (g < 4608) {
    int mat = (g >= 2304);              // 0: V1, 1: V2'
    int w = g - mat * 2304;
    int d = w >> 8, k = w & 255;
    float coef[9];
    #pragma unroll
    for (int dp = 0; dp < 9; ++dp) {
      if (!mat) {
        coef[dp] = A[dp][d];            // (A^T)[d][dp]
      } else {
        float s = 0.f;                  // (A^2)[dp][d]
        #pragma unroll
        for (int e = 0; e < 9; ++e) s += A[dp][e] * A[e][d];
        coef[dp] = s;
      }
    }
    const float* wm2row = Wm2 + (size_t)(mat * 256 + k) * 256;
    float acc = 0.f;
    #pragma unroll
    for (int it = 0; it < 4; ++it) {
      int h = lane + it * 64;           // coalesced across the wave
      float wp = 0.f;
      #pragma unroll
      for (int dp = 0; dp < 9; ++dp) wp = fmaf(coef[dp], Wreg[dp * 256 + h], wp);
      acc = fmaf(wp, wm2row[h], acc);
    }
    #pragma unroll
    for (int off = 32; off >= 1; off >>= 1) acc += __shfl_down(acc, off);
    if (lane == 0) vtab[5120 + g] = acc;
  } else if (g == 4608) {
    float c0 = 0.f;
    #pragma unroll
    for (int it = 0; it < 4; ++it) {
      int h = lane + it * 64;
      float cs = 0.f;
      #pragma unroll
      for (int d = 0; d < 9; ++d) cs += Wreg[d * 256 + h];
      c0 = fmaf(bm2[h], cs, c0);
    }
    #pragma unroll
    for (int off = 32; off >= 1; off >>= 1) c0 += __shfl_down(c0, off);
    if (lane == 0) vtab[9728] = c0 + breg[0];
  }
}

// ---- prep2b: wave-per-output.  U = A^T V1;
// final vtab: T1 @0 [9][256], Tw @2304 [9][256], C0' @4608
__global__ void prep2b_kernel(const float* __restrict__ Wm1,
                              const float* __restrict__ bm1,
                              float* __restrict__ vtab)
{
  const float A[9][9] = A_TABLE;
  const float* V1s = vtab + 5120;
  const float* V2s = vtab + 7424;
  const int lane = threadIdx.x & 63;
  const int g = blockIdx.x * 8 + (threadIdx.x >> 6);
  if (g < 4608) {
    int mat = (g >= 2304);              // 0: T1, 1: Tw
    int w = g - mat * 2304;
    int s = w >> 8, k = w & 255;
    const float* wm1row = Wm1 + (size_t)(mat * 256 + k) * 256;
    float acc = 0.f;
    #pragma unroll
    for (int it = 0; it < 4; ++it) {
      int h = lane + it * 64;
      float u = 0.f;
      #pragma unroll
      for (int d = 0; d < 9; ++d) u = fmaf(A[d][s], V1s[d * 256 + h], u);
      acc = fmaf(u, wm1row[h], acc);
    }
    #pragma unroll
    for (int off = 32; off >= 1; off >>= 1) acc += __shfl_down(acc, off);
    if (lane == 0) vtab[g] = acc + (mat ? V2s[s * 256 + k] : 0.f);
  } else if (g == 4608) {
    float c = 0.f;
    #pragma unroll
    for (int it = 0; it < 4; ++it) {
      int h = lane + it * 64;
      float vs = 0.f;
      #pragma unroll
      for (int d = 0; d < 9; ++d) vs += V1s[d * 256 + h];
      c = fmaf(bm1[h], vs, c);
    }
    #pragma unroll
    for (int off = 32; off >= 1; off >>= 1) c += __shfl_down(c, off);
    if (lane == 0) vtab[4608] = c + vtab[9728];
  }
}

// Phase order: A(l0->sT) | bar | gemm-sL | bar | B(w0->sT) | bar | gemm-sW | reduce.
// launch_bounds (512,2): arch cap 128 (no spill). Pressure held down structurally:
// mg loops unroll-1 + opaque offset (no B-frag CSE), Phase A 2x4-col passes.
// Target total = ~100 arch + 24 agpr <= 128 -> 4 waves/SIMD -> 2 blocks/CU.
__global__ void __launch_bounds__(NTHREADS, 2)
fused_kernel(const float* __restrict__ lags,
             const float* __restrict__ weather,
             const float* __restrict__ Wl1,
             const float* __restrict__ bl1,
             const float* __restrict__ gbn,
             const float* __restrict__ bbn,
             const float* __restrict__ bl2,
             const float* __restrict__ bw1,
             const float* __restrict__ bw2,
             const unsigned short* __restrict__ ws,
             const float* __restrict__ vtab,
             float* __restrict__ out)
{
  __shared__ __align__(16) unsigned short sBuf[SBUF_SHORTS];  // 74,240 B
  unsigned short* sT = sBuf;                     // l0, then reused for w0
  float* scratch = (float*)(sBuf + 36864);

  const int tid = threadIdx.x;
  const int wave = tid >> 6;
  const int lane16 = tid & 15;
  const int g4 = (tid >> 4) & 3;
  const int s0 = blockIdx.x * GSAMP;

  const unsigned short* Wl2t = ws;
  const unsigned short* Ww2t = ws + 65536;
  const unsigned short* Ww1p = ws + 131072;

  const int c0 = wave * 32 + lane16;       // wave's two output columns
  const int c1 = wave * 32 + 16 + lane16;

  // ---- Phase A: l0 = BN(tanh(lag*Wl1+bl1)) -> sT, lag-major, tile-major ----
  // Two 4-col passes (unroll 1): params 16 regs live instead of 32.
  {
    const float BNS = 0.99999500003750f;  // 1/sqrt(1+1e-5)
    const int samp = tid >> 5;            // 0..15
    const int chnk = tid & 31;            // fixed col chunk per thread
    #pragma unroll 1
    for (int hv = 0; hv < 2; ++hv) {
      const int h0 = (chnk << 3) + hv * 4;
      float4v w0 = *(const float4v*)(Wl1 + h0);
      float4v a0 = *(const float4v*)(bl1 + h0);
      float4v g0 = *(const float4v*)(gbn + h0);
      float4v q0 = *(const float4v*)(bbn + h0);
      #pragma unroll
      for (int e = 0; e < 4; ++e) g0[e] *= BNS;
      #pragma unroll
      for (int d = 0; d < 9; ++d) {       // d = lag
        int row = d * 16 + samp;
        float lag = lags[(s0 + samp) * NLAGS + d];
        float t[4];
        #pragma unroll
        for (int e = 0; e < 4; ++e) {
          float v = ftanh(fmaf(lag, w0[e], a0[e]));
          t[e] = fmaf(v, g0[e], q0[e]);
        }
        uint2 o;
        o.x = pkbf16(t[0], t[1]); o.y = pkbf16(t[2], t[3]);
        // same swizzled 16B chunk as before; hv selects its 8B half
        *(uint2*)(sT + tmC(row, chnk) + hv * 4) = o;
      }
    }
  }
  __syncthreads();   // B1: sT = l0 published

  float P[4] = {0.f, 0.f, 0.f, 0.f};   // per-lane partial outputs, samples g4*4+i

  // ---- gemm-sL (K=256): l1 = tanh(l0@Wl2+bl2); epilogue: P += <l1, T1> ----
  // m-grouped (3 groups of 3), unroll 1 + opaque offset: acc 24 AGPR live,
  // B-frags 8 regs live (no cross-group CSE).
  {
    float bia0 = bl2[c0], bia1 = bl2[c1];
    #pragma unroll 1
    for (int mg = 0; mg < 3; ++mg) {
      int lz = 0;
      asm volatile("" : "+v"(lz));       // opaque 0: blocks LICM/CSE across mg
      const unsigned short* Wb = Wl2t + lz;
      float4v acc0[3], acc1[3];
      #pragma unroll
      for (int mi = 0; mi < 3; ++mi) {
        float4v z = {0.f,0.f,0.f,0.f};
        acc0[mi] = z; acc1[mi] = z;
      }
      #pragma unroll
      for (int kk = 0; kk < 8; ++kk) {
        short8 b0 = *(const short8*)(Wb + c0 * 256 + kk * 32 + g4 * 8);
        short8 b1 = *(const short8*)(Wb + c1 * 256 + kk * 32 + g4 * 8);
        #pragma unroll
        for (int mi = 0; mi < 3; ++mi) {
          int m = mg * 3 + mi;
          short8 a = *(const short8*)(sT + tmC(m * 16 + lane16, kk * 4 + g4));
          acc0[mi] = mfma16(a, b0, acc0[mi]);
          acc1[mi] = mfma16(a, b1, acc1[mi]);
        }
      }
      #pragma unroll
      for (int mi = 0; mi < 3; ++mi) {
        int m = mg * 3 + mi;
        float t1c0 = vtab[m * 256 + c0];     // T1[lag=m][col]
        float t1c1 = vtab[m * 256 + c1];
        #pragma unroll
        for (int i = 0; i < 4; ++i) {
          float t0 = ftanh(acc0[mi][i] + bia0);   // l1, f32 (never quantized)
          float t1 = ftanh(acc1[mi][i] + bia1);
          P[i] = fmaf(t0, t1c0, P[i]);
          P[i] = fmaf(t1, t1c1, P[i]);
        }
      }
    }
  }
  __syncthreads();   // B2: all waves done reading l0; sT reusable

  // ---- Phase B: w0 = tanh(weather @ Ww1 + bw1) -> sT (K pad 8->32) ----
  // streamed per-m: only 8 AGPRs live at once.
  {
    short8 bf0 = *(const short8*)(Ww1p + c0 * 32 + g4 * 8);
    short8 bf1 = *(const short8*)(Ww1p + c1 * 32 + g4 * 8);
    float bia0 = bw1[c0], bia1 = bw1[c1];
    #pragma unroll
    for (int m = 0; m < 9; ++m) {         // m = lag tile; row-in-tile = samp = lane16
      S8 a8;
      if (g4 == 0) {
        const float* wp = weather + (size_t)(s0 + lane16) * 72 + m * 8;
        float4v x0 = *(const float4v*)(wp);
        float4v x1 = *(const float4v*)(wp + 4);
        a8.v = (short8){0,0,0,0,0,0,0,0};
        unsigned int p0 = pkbf16(x0[0], x0[1]), p1 = pkbf16(x0[2], x0[3]);
        unsigned int p2 = pkbf16(x1[0], x1[1]), p3 = pkbf16(x1[2], x1[3]);
        a8.u[0] = (unsigned short)p0; a8.u[1] = (unsigned short)(p0 >> 16);
        a8.u[2] = (unsigned short)p1; a8.u[3] = (unsigned short)(p1 >> 16);
        a8.u[4] = (unsigned short)p2; a8.u[5] = (unsigned short)(p2 >> 16);
        a8.u[6] = (unsigned short)p3; a8.u[7] = (unsigned short)(p3 >> 16);
      } else {
        a8.v = (short8){0,0,0,0,0,0,0,0};
      }
      float4v zz = {0.f, 0.f, 0.f, 0.f};
      float4v ac0 = mfma16(a8.v, bf0, zz);
      float4v ac1 = mfma16(a8.v, bf1, zz);
      #pragma unroll
      for (int i = 0; i < 4; ++i) {
        int row = m * 16 + g4 * 4 + i;    // C/D: col=lane&15, row=(lane>>4)*4+i
        unsigned int p = pkbf16(ftanh(ac0[i] + bia0), ftanh(ac1[i] + bia1));
        sT[tmE(row, c0)] = (unsigned short)p;
        sT[tmE(row, c1)] = (unsigned short)(p >> 16);
      }
    }
  }
  __syncthreads();   // B3: sT = w0 published

  // ---- gemm-sW (K=256): w1 = tanh(w0@Ww2+bw2); epilogue: P += <w1, Tw> ----
  {
    float bia0 = bw2[c0], bia1 = bw2[c1];
    #pragma unroll 1
    for (int mg = 0; mg < 3; ++mg) {
      int lz = 0;
      asm volatile("" : "+v"(lz));       // opaque 0: blocks LICM/CSE across mg
      const unsigned short* Wb = Ww2t + lz;
      float4v acc0[3], acc1[3];
      #pragma unroll
      for (int mi = 0; mi < 3; ++mi) {
        float4v z = {0.f,0.f,0.f,0.f};
        acc0[mi] = z; acc1[mi] = z;
      }
      #pragma unroll
      for (int kk = 0; kk < 8; ++kk) {
        short8 b0 = *(const short8*)(Wb + c0 * 256 + kk * 32 + g4 * 8);
        short8 b1 = *(const short8*)(Wb + c1 * 256 + kk * 32 + g4 * 8);
        #pragma unroll
        for (int mi = 0; mi < 3; ++mi) {
          int m = mg * 3 + mi;
          short8 a = *(const short8*)(sT + tmC(m * 16 + lane16, kk * 4 + g4));
          acc0[mi] = mfma16(a, b0, acc0[mi]);
          acc1[mi] = mfma16(a, b1, acc1[mi]);
        }
      }
      #pragma unroll
      for (int mi = 0; mi < 3; ++mi) {
        int m = mg * 3 + mi;
        float twc0 = vtab[2304 + m * 256 + c0];   // Tw[lag=m][col]
        float twc1 = vtab[2304 + m * 256 + c1];
        #pragma unroll
        for (int i = 0; i < 4; ++i) {
          float t0 = ftanh(acc0[mi][i] + bia0);   // w1, f32
          float t1 = ftanh(acc1[mi][i] + bia1);
          P[i] = fmaf(t0, twc0, P[i]);
          P[i] = fmaf(t1, twc1, P[i]);
        }
      }
    }
  }

  // ---- reduce: cols (shfl within lane16 groups) then waves (scratch) ----
  #pragma unroll
  for (int off = 8; off >= 1; off >>= 1) {
    #pragma unroll
    for (int i = 0; i < 4; ++i) P[i] += __shfl_down(P[i], off, 16);
  }
  if (lane16 == 0) {
    #pragma unroll
    for (int i = 0; i < 4; ++i) scratch[wave * 16 + g4 * 4 + i] = P[i];
  }
  __syncthreads();   // B4: scratch published
  if (tid < GSAMP) {
    float sum = 0.f;
    #pragma unroll
    for (int w = 0; w < 8; ++w) sum += scratch[w * 16 + tid];
    out[s0 + tid] = sum + vtab[4608];     // + C0' (breg + bm2-fold + bm1-fold)
  }
}

extern "C" void kernel_launch(void* const* d_in, const int* in_sizes, int n_in,
                              void* d_out, int out_size, void* d_ws, size_t ws_size,
                              hipStream_t stream) {
  const float* lags    = (const float*)d_in[0];
  const float* weather = (const float*)d_in[1];
  const float* Wl1     = (const float*)d_in[2];
  const float* bl1     = (const float*)d_in[3];
  const float* gbn     = (const float*)d_in[4];
  const float* bbn     = (const float*)d_in[5];
  const float* Wl2     = (const float*)d_in[6];
  const float* bl2     = (const float*)d_in[7];
  const float* Ww1     = (const float*)d_in[8];
  const float* bw1     = (const float*)d_in[9];
  const float* Ww2     = (const float*)d_in[10];
  const float* bw2     = (const float*)d_in[11];
  const float* Wm1     = (const float*)d_in[12];
  const float* bm1     = (const float*)d_in[13];
  const float* Wm2     = (const float*)d_in[14];
  const float* bm2     = (const float*)d_in[15];
  const float* Wreg    = (const float*)d_in[16];
  const float* breg    = (const float*)d_in[17];
  unsigned short* ws = (unsigned short*)d_ws;
  float* vtab = (float*)(ws + 139264);    // byte offset 278,528 (16B-aligned)

  // prep_all: 272 staging blocks + 577 prep2a wave-blocks = 849
  prep_all<<<849, 512, 0, stream>>>(Wl2, Ww2, Ww1, Wm2, Wreg, bm2, breg, ws, vtab);
  prep2b_kernel<<<577, 512, 0, stream>>>(Wm1, bm1, vtab);

  const int nblocks = 32768 / GSAMP;  // 2048
  fused_kernel<<<nblocks, NTHREADS, 0, stream>>>(
      lags, weather, Wl1, bl1, gbn, bbn, bl2, bw1, bw2,
      ws, vtab, (float*)d_out);
}

// Round 7
// 232.386 us; speedup vs baseline: 1.3427x; 1.3427x over previous
//
#include <hip/hip_runtime.h>

typedef __attribute__((ext_vector_type(8))) short short8;
typedef __attribute__((ext_vector_type(4))) float float4v;

#define NLAGS 9
#define HID 256
#define GSAMP 16
#define NTHREADS 512
// ONE tile buffer (w0) + 128 f32 wave-partials + 144 f32 lag-LUT partials
#define SBUF_SHORTS (36864 + 256 + 288)   // 74,816 B

// LUT geometry: 9 rows (per lag-slot d), 2048 knots over [-8, 8]
#define NK 2048
#define LUT_STRIDE 2056                   // padded row stride (floats)
#define SLO -8.0f
#define KINV 128.0f                       // NK / 16

union S8 { short8 v; unsigned short u[8]; };

__device__ __forceinline__ unsigned short f2b(float f) {
  union { float f; unsigned int i; } c; c.f = f;
  return (unsigned short)((c.i + 0x7FFFu + ((c.i >> 16) & 1u)) >> 16);  // RNE
}
__device__ __forceinline__ float sane(float x) {
  return (__builtin_isfinite(x) && fabsf(x) < 1e30f) ? x : 0.0f;
}
// HW packed f32->bf16 (RNE), 1 VALU op for 2 conversions
__device__ __forceinline__ unsigned int pkbf16(float lo, float hi) {
  unsigned int r;
  asm("v_cvt_pk_bf16_f32 %0, %1, %2" : "=v"(r) : "v"(lo), "v"(hi));
  return r;
}
// unclamped tanh: exp->0 gives -1, exp->inf gives +1; finite-in => finite-out
// BLACKLIST (r8-r10 bisect): bias-init-in-MFMA-C and exp2f-tanh broke correctness.
// REGISTER/OCCUPANCY MODEL (R1-R6, closed):
//   Arch cap = 256/min_waves ((512,2)->128, (512,3)->84, (512,4)->64); demand
//   above cap => scratch spill. HW occupancy = floor(512/(arch+agpr)) waves/SIMD.
//   R6 PROVED occupancy is NOT the bottleneck: 43% occ with serialized unroll-1
//   code = 237us vs 22% occ full-ILP r0 = 176us. Per-wave ILP > wave count here.
//   => keep (512,2), full unrolls, natural register usage; NO pressure hacks.
__device__ __forceinline__ float ftanh(float x) {
  float t = __expf(2.0f * x);
  return 1.0f - 2.0f * __builtin_amdgcn_rcpf(t + 1.0f);
}
__device__ __forceinline__ float4v mfma16(short8 a, short8 b, float4v c) {
  return __builtin_amdgcn_mfma_f32_16x16x32_bf16(a, b, c, 0, 0, 0);
}

// ---- tile-major bf16 LDS layout: [tile m][kk-block of 32 cols][row 0..15][col&31]
// XOR bank swizzle: rotate the 32B sub-chunk by ((col>>5)^(row>>2))&3.
__device__ __forceinline__ int tmC(int row, int c) {        // chunk c = col/8, 0..31
  int base = ((row >> 4) * 8 + (c >> 2)) * 512 + (row & 15) * 32 + (c & 3) * 8;
  return base ^ ((((c >> 2) ^ (row >> 2)) & 3) << 4);
}
__device__ __forceinline__ int tmE(int row, int col) {      // single element
  int base = ((row >> 4) * 8 + (col >> 5)) * 512 + (row & 15) * 32 + (col & 31);
  return base ^ ((((col >> 5) ^ (row >> 2)) & 3) << 4);
}

#define A_TABLE { \
    {0,0,0,0,0,0,0,0,1}, \
    {1,0,0,0,0,0,0,0,0}, \
    {1.f/3,2.f/3,0,0,0,0,0,0,0}, \
    {0.2f,0.4f,0.4f,0,0,0,0,0,0}, \
    {0,0.2f,0.4f,0.4f,0,0,0,0,0}, \
    {0,0,0.2f,0.4f,0.4f,0,0,0,0}, \
    {0,0,0,0.2f,0.4f,0.4f,0,0,0}, \
    {0,0,0,0,0.25f,0.5f,0.25f,0,0}, \
    {0,0,0,0,0,1.f/3,1.f/3,1.f/3,0}, \
  }

// ---- prep_all: (blocks 0..143) stage Ww2t/Ww1p bf16; (blocks 144..720) prep2a.
// ws layout (shorts): [0..65535] = f32 LUT region (written by prep3, 9x2056 f32);
//   Ww2t[256][256] @65536, Ww1p[256][32] @131072 (K pad 8->32).
// vtab staging (f32): V1 @5120 [9][256], V2' @7424 [9][256], C0 @9728
__global__ void prep_all(const float* __restrict__ Ww2,
                         const float* __restrict__ Ww1,
                         const float* __restrict__ Wm2,
                         const float* __restrict__ Wreg,
                         const float* __restrict__ bm2,
                         const float* __restrict__ breg,
                         unsigned short* __restrict__ ws,
                         float* __restrict__ vtab)
{
  const int b = blockIdx.x;
  if (b < 144) {
    int idx = b * 512 + threadIdx.x + 65536;   // 65536..139263
    if (idx < 131072) {
      int j = idx - 65536; int n = j >> 8, k = j & 255;
      ws[idx] = f2b(sane(Ww2[k * 256 + n]));
    } else {
      int j = idx - 131072; int n = j >> 5, k = j & 31;
      ws[idx] = (k < 8) ? f2b(sane(Ww1[k * 256 + n])) : (unsigned short)0;
    }
    return;
  }
  // ---- prep2a: one wave per output element ----
  const float A[9][9] = A_TABLE;
  const int lane = threadIdx.x & 63;
  const int g = (b - 144) * 8 + (threadIdx.x >> 6);
  if (g < 4608) {
    int mat = (g >= 2304);              // 0: V1, 1: V2'
    int w = g - mat * 2304;
    int d = w >> 8, k = w & 255;
    float coef[9];
    #pragma unroll
    for (int dp = 0; dp < 9; ++dp) {
      if (!mat) {
        coef[dp] = A[dp][d];            // (A^T)[d][dp]
      } else {
        float s = 0.f;                  // (A^2)[dp][d]
        #pragma unroll
        for (int e = 0; e < 9; ++e) s += A[dp][e] * A[e][d];
        coef[dp] = s;
      }
    }
    const float* wm2row = Wm2 + (size_t)(mat * 256 + k) * 256;
    float acc = 0.f;
    #pragma unroll
    for (int it = 0; it < 4; ++it) {
      int h = lane + it * 64;           // coalesced across the wave
      float wp = 0.f;
      #pragma unroll
      for (int dp = 0; dp < 9; ++dp) wp = fmaf(coef[dp], Wreg[dp * 256 + h], wp);
      acc = fmaf(wp, wm2row[h], acc);
    }
    #pragma unroll
    for (int off = 32; off >= 1; off >>= 1) acc += __shfl_down(acc, off);
    if (lane == 0) vtab[5120 + g] = acc;
  } else if (g == 4608) {
    float c0 = 0.f;
    #pragma unroll
    for (int it = 0; it < 4; ++it) {
      int h = lane + it * 64;
      float cs = 0.f;
      #pragma unroll
      for (int d = 0; d < 9; ++d) cs += Wreg[d * 256 + h];
      c0 = fmaf(bm2[h], cs, c0);
    }
    #pragma unroll
    for (int off = 32; off >= 1; off >>= 1) c0 += __shfl_down(c0, off);
    if (lane == 0) vtab[9728] = c0 + breg[0];
  }
}

// ---- prep2b: wave-per-output.  U = A^T V1;
// final vtab: T1 @0 [9][256], Tw @2304 [9][256], C0' @4608
__global__ void prep2b_kernel(const float* __restrict__ Wm1,
                              const float* __restrict__ bm1,
                              float* __restrict__ vtab)
{
  const float A[9][9] = A_TABLE;
  const float* V1s = vtab + 5120;
  const float* V2s = vtab + 7424;
  const int lane = threadIdx.x & 63;
  const int g = blockIdx.x * 8 + (threadIdx.x >> 6);
  if (g < 4608) {
    int mat = (g >= 2304);              // 0: T1, 1: Tw
    int w = g - mat * 2304;
    int s = w >> 8, k = w & 255;
    const float* wm1row = Wm1 + (size_t)(mat * 256 + k) * 256;
    float acc = 0.f;
    #pragma unroll
    for (int it = 0; it < 4; ++it) {
      int h = lane + it * 64;
      float u = 0.f;
      #pragma unroll
      for (int d = 0; d < 9; ++d) u = fmaf(A[d][s], V1s[d * 256 + h], u);
      acc = fmaf(u, wm1row[h], acc);
    }
    #pragma unroll
    for (int off = 32; off >= 1; off >>= 1) acc += __shfl_down(acc, off);
    if (lane == 0) vtab[g] = acc + (mat ? V2s[s * 256 + k] : 0.f);
  } else if (g == 4608) {
    float c = 0.f;
    #pragma unroll
    for (int it = 0; it < 4; ++it) {
      int h = lane + it * 64;
      float vs = 0.f;
      #pragma unroll
      for (int d = 0; d < 9; ++d) vs += V1s[d * 256 + h];
      c = fmaf(bm1[h], vs, c);
    }
    #pragma unroll
    for (int off = 32; off >= 1; off >>= 1) c += __shfl_down(c, off);
    if (lane == 0) vtab[4608] = c + vtab[9728];
  }
}

// ---- prep3: build the lags-branch LUT.  The ENTIRE l-branch contribution to
// the output is, per lag-slot d, a scalar function of the scalar lag x:
//   f_d(x) = sum_h tanh( l0(x) @ Wl2 + bl2 )[h] * T1[d,h],
//   l0(x)  = BNS*g ⊙ tanh(x*Wl1 + bl1) + bbn      (256-vec, depends only on x)
// Tabulate f_d at NK=2048 knots over [-8,8] in FULL f32 (more accurate than the
// bf16 GEMM it replaces).  Block b computes knots b*8..b*8+7; 256 threads.
__global__ void prep3_lut(const float* __restrict__ Wl1,
                          const float* __restrict__ bl1,
                          const float* __restrict__ gbn,
                          const float* __restrict__ bbn,
                          const float* __restrict__ Wl2,
                          const float* __restrict__ bl2,
                          const float* __restrict__ vtab,   // T1 @0 [9][256]
                          float* __restrict__ lutf)         // [9][LUT_STRIDE]
{
  __shared__ float l0s[8][256];
  __shared__ float red[8][9][4];
  const int tid = threadIdx.x;        // 0..255
  const int b = blockIdx.x;           // 0..255
  const float BNS = 0.99999500003750f;  // 1/sqrt(1+1e-5)
  {
    float w = Wl1[tid], a = bl1[tid], g = gbn[tid] * BNS, q = bbn[tid];
    #pragma unroll
    for (int j = 0; j < 8; ++j) {
      float s = SLO + (float)(b * 8 + j) * 0.0078125f;   // 16/2048 exact
      l0s[j][tid] = fmaf(ftanh(fmaf(s, w, a)), g, q);
    }
  }
  __syncthreads();
  float z[8];
  {
    float bz = bl2[tid];
    #pragma unroll
    for (int j = 0; j < 8; ++j) z[j] = bz;
  }
  for (int k = 0; k < 256; ++k) {
    float wv = Wl2[k * 256 + tid];          // coalesced across tid
    #pragma unroll
    for (int j = 0; j < 8; ++j) z[j] = fmaf(l0s[j][k], wv, z[j]);
  }
  float t[8];
  #pragma unroll
  for (int j = 0; j < 8; ++j) t[j] = ftanh(z[j]);
  const int lane = tid & 63, w4 = tid >> 6;
  for (int d = 0; d < 9; ++d) {
    float T1h = vtab[d * 256 + tid];
    #pragma unroll
    for (int j = 0; j < 8; ++j) {
      float v = t[j] * T1h;
      #pragma unroll
      for (int off = 32; off >= 1; off >>= 1) v += __shfl_down(v, off);
      if (lane == 0) red[j][d][w4] = v;
    }
  }
  __syncthreads();
  if (tid < 72) {
    int j = tid / 9, d = tid - j * 9;
    float v = red[j][d][0] + red[j][d][1] + red[j][d][2] + red[j][d][3];
    lutf[d * LUT_STRIDE + (b * 8 + j)] = v;
  }
}

// Fused (v7): lag-LUT lerps | Phase B (w0->sT) | bar | gemm-sW | reduce | out.
// l-branch (Phase A + gemm-sL + 144 tanh/thread) fully replaced by 144 lerps.
// r0-proven code shapes: full unrolls, full 9-tile acc, (512,2), 1 block/CU.
__global__ void __launch_bounds__(NTHREADS, 2)
fused_kernel(const float* __restrict__ lags,
             const float* __restrict__ weather,
             const float* __restrict__ bw1,
             const float* __restrict__ bw2,
             const unsigned short* __restrict__ ws,
             const float* __restrict__ vtab,
             float* __restrict__ out)
{
  __shared__ __align__(16) unsigned short sBuf[SBUF_SHORTS];  // 74,816 B
  unsigned short* sT = sBuf;
  float* scratch  = (float*)(sBuf + 36864);        // 128 f32 wave partials
  float* scratch2 = (float*)(sBuf + 36864 + 256);  // 144 f32 lag-LUT partials

  const int tid = threadIdx.x;
  const int wave = tid >> 6;
  const int lane16 = tid & 15;
  const int g4 = (tid >> 4) & 3;
  const int s0 = blockIdx.x * GSAMP;

  const float* lutf = (const float*)ws;            // 9 x LUT_STRIDE f32
  const unsigned short* Ww2t = ws + 65536;
  const unsigned short* Ww1p = ws + 131072;

  const int c0 = wave * 32 + lane16;       // wave's two output columns
  const int c1 = wave * 32 + 16 + lane16;

  // ---- lag-LUT: threads 0..143, one (sample, d) each ----
  if (tid < 144) {
    int samp = tid / 9, d = tid - samp * 9;
    float x = lags[(s0 + samp) * NLAGS + d];
    float tp = (x - SLO) * KINV;
    tp = fminf(fmaxf(tp, 0.0f), (float)(NK - 2) + 0.999f);
    int j = (int)tp; float fr = tp - (float)j;
    const float* row = lutf + d * LUT_STRIDE;
    float lo = row[j], hi = row[j + 1];
    scratch2[tid] = fmaf(fr, hi - lo, lo);   // samp*9 + d
  }

  // ---- Phase B: w0 = tanh(weather @ Ww1 + bw1) -> sT (K pad 8->32) ----
  {
    short8 bf0 = *(const short8*)(Ww1p + c0 * 32 + g4 * 8);
    short8 bf1 = *(const short8*)(Ww1p + c1 * 32 + g4 * 8);
    float bia0 = bw1[c0], bia1 = bw1[c1];
    #pragma unroll
    for (int m = 0; m < 9; ++m) {         // m = lag tile; row-in-tile = lane16
      S8 a8;
      if (g4 == 0) {
        const float* wp = weather + (size_t)(s0 + lane16) * 72 + m * 8;
        float4v x0 = *(const float4v*)(wp);
        float4v x1 = *(const float4v*)(wp + 4);
        a8.v = (short8){0,0,0,0,0,0,0,0};
        unsigned int p0 = pkbf16(x0[0], x0[1]), p1 = pkbf16(x0[2], x0[3]);
        unsigned int p2 = pkbf16(x1[0], x1[1]), p3 = pkbf16(x1[2], x1[3]);
        a8.u[0] = (unsigned short)p0; a8.u[1] = (unsigned short)(p0 >> 16);
        a8.u[2] = (unsigned short)p1; a8.u[3] = (unsigned short)(p1 >> 16);
        a8.u[4] = (unsigned short)p2; a8.u[5] = (unsigned short)(p2 >> 16);
        a8.u[6] = (unsigned short)p3; a8.u[7] = (unsigned short)(p3 >> 16);
      } else {
        a8.v = (short8){0,0,0,0,0,0,0,0};
      }
      float4v zz = {0.f, 0.f, 0.f, 0.f};
      float4v ac0 = mfma16(a8.v, bf0, zz);
      float4v ac1 = mfma16(a8.v, bf1, zz);
      #pragma unroll
      for (int i = 0; i < 4; ++i) {
        int row = m * 16 + g4 * 4 + i;    // C/D: col=lane&15, row=(lane>>4)*4+i
        unsigned int p = pkbf16(ftanh(ac0[i] + bia0), ftanh(ac1[i] + bia1));
        sT[tmE(row, c0)] = (unsigned short)p;
        sT[tmE(row, c1)] = (unsigned short)(p >> 16);
      }
    }
  }
  __syncthreads();   // B1: sT = w0 and scratch2 published

  float P[4] = {0.f, 0.f, 0.f, 0.f};   // per-lane partial outputs, samples g4*4+i

  // ---- gemm-sW (K=256): w1 = tanh(w0@Ww2+bw2); epilogue: P += <w1, Tw> ----
  {
    float4v acc0[9], acc1[9];
    #pragma unroll
    for (int m = 0; m < 9; ++m) {
      float4v z = {0.f,0.f,0.f,0.f};
      acc0[m] = z; acc1[m] = z;
    }
    #pragma unroll
    for (int kk = 0; kk < 8; ++kk) {
      short8 b0 = *(const short8*)(Ww2t + c0 * 256 + kk * 32 + g4 * 8);
      short8 b1 = *(const short8*)(Ww2t + c1 * 256 + kk * 32 + g4 * 8);
      #pragma unroll
      for (int m = 0; m < 9; ++m) {
        short8 a = *(const short8*)(sT + tmC(m * 16 + lane16, kk * 4 + g4));
        acc0[m] = mfma16(a, b0, acc0[m]);
        acc1[m] = mfma16(a, b1, acc1[m]);
      }
    }
    float twc0[9], twc1[9];
    #pragma unroll
    for (int m = 0; m < 9; ++m) {
      twc0[m] = vtab[2304 + m * 256 + c0];   // Tw[lag=m][col]
      twc1[m] = vtab[2304 + m * 256 + c1];
    }
    float bia0 = bw2[c0], bia1 = bw2[c1];
    #pragma unroll
    for (int m = 0; m < 9; ++m) {
      #pragma unroll
      for (int i = 0; i < 4; ++i) {
        float t0 = ftanh(acc0[m][i] + bia0);   // w1, f32 (never quantized)
        float t1 = ftanh(acc1[m][i] + bia1);
        P[i] = fmaf(t0, twc0[m], P[i]);
        P[i] = fmaf(t1, twc1[m], P[i]);
      }
    }
  }

  // ---- reduce: cols (shfl within lane16 groups) then waves (scratch) ----
  #pragma unroll
  for (int off = 8; off >= 1; off >>= 1) {
    #pragma unroll
    for (int i = 0; i < 4; ++i) P[i] += __shfl_down(P[i], off, 16);
  }
  if (lane16 == 0) {
    #pragma unroll
    for (int i = 0; i < 4; ++i) scratch[wave * 16 + g4 * 4 + i] = P[i];
  }
  __syncthreads();   // B2: scratch published
  if (tid < GSAMP) {
    float sum = 0.f;
    #pragma unroll
    for (int w = 0; w < 8; ++w) sum += scratch[w * 16 + tid];
    float lsum = 0.f;
    #pragma unroll
    for (int d = 0; d < 9; ++d) lsum += scratch2[tid * 9 + d];
    out[s0 + tid] = sum + lsum + vtab[4608];   // + C0'
  }
}

extern "C" void kernel_launch(void* const* d_in, const int* in_sizes, int n_in,
                              void* d_out, int out_size, void* d_ws, size_t ws_size,
                              hipStream_t stream) {
  const float* lags    = (const float*)d_in[0];
  const float* weather = (const float*)d_in[1];
  const float* Wl1     = (const float*)d_in[2];
  const float* bl1     = (const float*)d_in[3];
  const float* gbn     = (const float*)d_in[4];
  const float* bbn     = (const float*)d_in[5];
  const float* Wl2     = (const float*)d_in[6];
  const float* bl2     = (const float*)d_in[7];
  const float* Ww1     = (const float*)d_in[8];
  const float* bw1     = (const float*)d_in[9];
  const float* Ww2     = (const float*)d_in[10];
  const float* bw2     = (const float*)d_in[11];
  const float* Wm1     = (const float*)d_in[12];
  const float* bm1     = (const float*)d_in[13];
  const float* Wm2     = (const float*)d_in[14];
  const float* bm2     = (const float*)d_in[15];
  const float* Wreg    = (const float*)d_in[16];
  const float* breg    = (const float*)d_in[17];
  unsigned short* ws = (unsigned short*)d_ws;
  float* vtab = (float*)(ws + 139264);    // byte offset 278,528 (16B-aligned)
  float* lutf = (float*)ws;               // reuses dead Wl2t region (128KB)

  // prep_all: 144 staging blocks + 577 prep2a wave-blocks = 721
  prep_all<<<721, 512, 0, stream>>>(Ww2, Ww1, Wm2, Wreg, bm2, breg, ws, vtab);
  prep2b_kernel<<<577, 512, 0, stream>>>(Wm1, bm1, vtab);
  prep3_lut<<<256, 256, 0, stream>>>(Wl1, bl1, gbn, bbn, Wl2, bl2, vtab, lutf);

  const int nblocks = 32768 / GSAMP;  // 2048
  fused_kernel<<<nblocks, NTHREADS, 0, stream>>>(
      lags, weather, bw1, bw2, ws, vtab, (float*)d_out);
}

// Round 8
// 213.217 us; speedup vs baseline: 1.4634x; 1.0899x over previous
//
#include <hip/hip_runtime.h>

typedef __attribute__((ext_vector_type(8))) short short8;
typedef __attribute__((ext_vector_type(4))) float float4v;

#define NLAGS 9
#define HID 256
#define GSAMP 16
#define NTHREADS 512
// ONE tile buffer (w0) + 128 f32 wave-partials + 144 f32 lag-LUT partials
#define SBUF_SHORTS (36864 + 256 + 288)   // 74,816 B

// LUT geometry: 9 rows (per lag-slot d), 2048 knots over [-8, 8]
#define NK 2048
#define LUT_STRIDE 2056                   // padded row stride (floats)
#define SLO -8.0f
#define KINV 128.0f                       // NK / 16

union S8 { short8 v; unsigned short u[8]; };

__device__ __forceinline__ unsigned short f2b(float f) {
  union { float f; unsigned int i; } c; c.f = f;
  return (unsigned short)((c.i + 0x7FFFu + ((c.i >> 16) & 1u)) >> 16);  // RNE
}
__device__ __forceinline__ float sane(float x) {
  return (__builtin_isfinite(x) && fabsf(x) < 1e30f) ? x : 0.0f;
}
// HW packed f32->bf16 (RNE), 1 VALU op for 2 conversions
__device__ __forceinline__ unsigned int pkbf16(float lo, float hi) {
  unsigned int r;
  asm("v_cvt_pk_bf16_f32 %0, %1, %2" : "=v"(r) : "v"(lo), "v"(hi));
  return r;
}
// unclamped tanh: exp->0 gives -1, exp->inf gives +1; finite-in => finite-out
// BLACKLIST (r8-r10 bisect): bias-init-in-MFMA-C and exp2f-tanh broke correctness.
// REGISTER/OCCUPANCY MODEL (R1-R6, closed):
//   Arch cap = 256/min_waves ((512,2)->128, (512,3)->84, (512,4)->64); demand
//   above cap => scratch spill. HW occupancy = floor(512/(arch+agpr)) waves/SIMD.
//   R6 PROVED occupancy is NOT the fused bottleneck: keep (512,2), full unrolls.
// R7 FINDING: l-branch -> 9x1D LUT passed at identical absmax; fused 200->112us,
//   bank conflicts -> 0. Remaining cost split: fused ~112us, prep chain ~120us.
//   prep3 at 256 blocks = 1 block/CU = 4 waves/CU -> latency-bound. This round:
//   prep3 regrid 1024 blocks x 2 knots (16 waves/CU).
__device__ __forceinline__ float ftanh(float x) {
  float t = __expf(2.0f * x);
  return 1.0f - 2.0f * __builtin_amdgcn_rcpf(t + 1.0f);
}
__device__ __forceinline__ float4v mfma16(short8 a, short8 b, float4v c) {
  return __builtin_amdgcn_mfma_f32_16x16x32_bf16(a, b, c, 0, 0, 0);
}

// ---- tile-major bf16 LDS layout: [tile m][kk-block of 32 cols][row 0..15][col&31]
// XOR bank swizzle: rotate the 32B sub-chunk by ((col>>5)^(row>>2))&3.
__device__ __forceinline__ int tmC(int row, int c) {        // chunk c = col/8, 0..31
  int base = ((row >> 4) * 8 + (c >> 2)) * 512 + (row & 15) * 32 + (c & 3) * 8;
  return base ^ ((((c >> 2) ^ (row >> 2)) & 3) << 4);
}
__device__ __forceinline__ int tmE(int row, int col) {      // single element
  int base = ((row >> 4) * 8 + (col >> 5)) * 512 + (row & 15) * 32 + (col & 31);
  return base ^ ((((col >> 5) ^ (row >> 2)) & 3) << 4);
}

#define A_TABLE { \
    {0,0,0,0,0,0,0,0,1}, \
    {1,0,0,0,0,0,0,0,0}, \
    {1.f/3,2.f/3,0,0,0,0,0,0,0}, \
    {0.2f,0.4f,0.4f,0,0,0,0,0,0}, \
    {0,0.2f,0.4f,0.4f,0,0,0,0,0}, \
    {0,0,0.2f,0.4f,0.4f,0,0,0,0}, \
    {0,0,0,0.2f,0.4f,0.4f,0,0,0}, \
    {0,0,0,0,0.25f,0.5f,0.25f,0,0}, \
    {0,0,0,0,0,1.f/3,1.f/3,1.f/3,0}, \
  }

// ---- prep_all: (blocks 0..143) stage Ww2t/Ww1p bf16; (blocks 144..720) prep2a.
// ws layout (shorts): [0..65535] = f32 LUT region (written by prep3, 9x2056 f32);
//   Ww2t[256][256] @65536, Ww1p[256][32] @131072 (K pad 8->32).
// vtab staging (f32): V1 @5120 [9][256], V2' @7424 [9][256], C0 @9728
__global__ void prep_all(const float* __restrict__ Ww2,
                         const float* __restrict__ Ww1,
                         const float* __restrict__ Wm2,
                         const float* __restrict__ Wreg,
                         const float* __restrict__ bm2,
                         const float* __restrict__ breg,
                         unsigned short* __restrict__ ws,
                         float* __restrict__ vtab)
{
  const int b = blockIdx.x;
  if (b < 144) {
    int idx = b * 512 + threadIdx.x + 65536;   // 65536..139263
    if (idx < 131072) {
      int j = idx - 65536; int n = j >> 8, k = j & 255;
      ws[idx] = f2b(sane(Ww2[k * 256 + n]));
    } else {
      int j = idx - 131072; int n = j >> 5, k = j & 31;
      ws[idx] = (k < 8) ? f2b(sane(Ww1[k * 256 + n])) : (unsigned short)0;
    }
    return;
  }
  // ---- prep2a: one wave per output element ----
  const float A[9][9] = A_TABLE;
  const int lane = threadIdx.x & 63;
  const int g = (b - 144) * 8 + (threadIdx.x >> 6);
  if (g < 4608) {
    int mat = (g >= 2304);              // 0: V1, 1: V2'
    int w = g - mat * 2304;
    int d = w >> 8, k = w & 255;
    float coef[9];
    #pragma unroll
    for (int dp = 0; dp < 9; ++dp) {
      if (!mat) {
        coef[dp] = A[dp][d];            // (A^T)[d][dp]
      } else {
        float s = 0.f;                  // (A^2)[dp][d]
        #pragma unroll
        for (int e = 0; e < 9; ++e) s += A[dp][e] * A[e][d];
        coef[dp] = s;
      }
    }
    const float* wm2row = Wm2 + (size_t)(mat * 256 + k) * 256;
    float acc = 0.f;
    #pragma unroll
    for (int it = 0; it < 4; ++it) {
      int h = lane + it * 64;           // coalesced across the wave
      float wp = 0.f;
      #pragma unroll
      for (int dp = 0; dp < 9; ++dp) wp = fmaf(coef[dp], Wreg[dp * 256 + h], wp);
      acc = fmaf(wp, wm2row[h], acc);
    }
    #pragma unroll
    for (int off = 32; off >= 1; off >>= 1) acc += __shfl_down(acc, off);
    if (lane == 0) vtab[5120 + g] = acc;
  } else if (g == 4608) {
    float c0 = 0.f;
    #pragma unroll
    for (int it = 0; it < 4; ++it) {
      int h = lane + it * 64;
      float cs = 0.f;
      #pragma unroll
      for (int d = 0; d < 9; ++d) cs += Wreg[d * 256 + h];
      c0 = fmaf(bm2[h], cs, c0);
    }
    #pragma unroll
    for (int off = 32; off >= 1; off >>= 1) c0 += __shfl_down(c0, off);
    if (lane == 0) vtab[9728] = c0 + breg[0];
  }
}

// ---- prep2b: wave-per-output.  U = A^T V1;
// final vtab: T1 @0 [9][256], Tw @2304 [9][256], C0' @4608
__global__ void prep2b_kernel(const float* __restrict__ Wm1,
                              const float* __restrict__ bm1,
                              float* __restrict__ vtab)
{
  const float A[9][9] = A_TABLE;
  const float* V1s = vtab + 5120;
  const float* V2s = vtab + 7424;
  const int lane = threadIdx.x & 63;
  const int g = blockIdx.x * 8 + (threadIdx.x >> 6);
  if (g < 4608) {
    int mat = (g >= 2304);              // 0: T1, 1: Tw
    int w = g - mat * 2304;
    int s = w >> 8, k = w & 255;
    const float* wm1row = Wm1 + (size_t)(mat * 256 + k) * 256;
    float acc = 0.f;
    #pragma unroll
    for (int it = 0; it < 4; ++it) {
      int h = lane + it * 64;
      float u = 0.f;
      #pragma unroll
      for (int d = 0; d < 9; ++d) u = fmaf(A[d][s], V1s[d * 256 + h], u);
      acc = fmaf(u, wm1row[h], acc);
    }
    #pragma unroll
    for (int off = 32; off >= 1; off >>= 1) acc += __shfl_down(acc, off);
    if (lane == 0) vtab[g] = acc + (mat ? V2s[s * 256 + k] : 0.f);
  } else if (g == 4608) {
    float c = 0.f;
    #pragma unroll
    for (int it = 0; it < 4; ++it) {
      int h = lane + it * 64;
      float vs = 0.f;
      #pragma unroll
      for (int d = 0; d < 9; ++d) vs += V1s[d * 256 + h];
      c = fmaf(bm1[h], vs, c);
    }
    #pragma unroll
    for (int off = 32; off >= 1; off >>= 1) c += __shfl_down(c, off);
    if (lane == 0) vtab[4608] = c + vtab[9728];
  }
}

// ---- prep3: build the lags-branch LUT.  Per lag-slot d, scalar function:
//   f_d(x) = sum_h tanh( l0(x) @ Wl2 + bl2 )[h] * T1[d,h]
// R7->R8: regrid 256x8knots -> 1024x2knots. Same work, 4x blocks/CU (16 waves/CU)
// so the 256-iteration L2-load chain has TLP to hide behind; 2 FMA chains/thread.
__global__ void prep3_lut(const float* __restrict__ Wl1,
                          const float* __restrict__ bl1,
                          const float* __restrict__ gbn,
                          const float* __restrict__ bbn,
                          const float* __restrict__ Wl2,
                          const float* __restrict__ bl2,
                          const float* __restrict__ vtab,   // T1 @0 [9][256]
                          float* __restrict__ lutf)         // [9][LUT_STRIDE]
{
  __shared__ float l0s[2][256];
  __shared__ float red[2][9][4];
  const int tid = threadIdx.x;        // 0..255
  const int b = blockIdx.x;           // 0..1023, knots b*2, b*2+1
  const float BNS = 0.99999500003750f;  // 1/sqrt(1+1e-5)
  {
    float w = Wl1[tid], a = bl1[tid], g = gbn[tid] * BNS, q = bbn[tid];
    #pragma unroll
    for (int j = 0; j < 2; ++j) {
      float s = SLO + (float)(b * 2 + j) * 0.0078125f;   // 16/2048 exact
      l0s[j][tid] = fmaf(ftanh(fmaf(s, w, a)), g, q);
    }
  }
  __syncthreads();
  float z0 = bl2[tid], z1 = z0;
  #pragma unroll 8
  for (int k = 0; k < 256; ++k) {
    float wv = Wl2[k * 256 + tid];          // coalesced across tid; L2-hot
    z0 = fmaf(l0s[0][k], wv, z0);
    z1 = fmaf(l0s[1][k], wv, z1);
  }
  float t0 = ftanh(z0), t1 = ftanh(z1);
  const int lane = tid & 63, w4 = tid >> 6;
  for (int d = 0; d < 9; ++d) {
    float T1h = vtab[d * 256 + tid];
    float v0 = t0 * T1h, v1 = t1 * T1h;
    #pragma unroll
    for (int off = 32; off >= 1; off >>= 1) {
      v0 += __shfl_down(v0, off);
      v1 += __shfl_down(v1, off);
    }
    if (lane == 0) { red[0][d][w4] = v0; red[1][d][w4] = v1; }
  }
  __syncthreads();
  if (tid < 18) {
    int j = tid / 9, d = tid - j * 9;
    float v = red[j][d][0] + red[j][d][1] + red[j][d][2] + red[j][d][3];
    lutf[d * LUT_STRIDE + (b * 2 + j)] = v;
  }
}

// Fused (v8 = v7 unchanged): lag-LUT lerps | Phase B (w0->sT) | bar | gemm-sW
// | reduce | out.
__global__ void __launch_bounds__(NTHREADS, 2)
fused_kernel(const float* __restrict__ lags,
             const float* __restrict__ weather,
             const float* __restrict__ bw1,
             const float* __restrict__ bw2,
             const unsigned short* __restrict__ ws,
             const float* __restrict__ vtab,
             float* __restrict__ out)
{
  __shared__ __align__(16) unsigned short sBuf[SBUF_SHORTS];  // 74,816 B
  unsigned short* sT = sBuf;
  float* scratch  = (float*)(sBuf + 36864);        // 128 f32 wave partials
  float* scratch2 = (float*)(sBuf + 36864 + 256);  // 144 f32 lag-LUT partials

  const int tid = threadIdx.x;
  const int wave = tid >> 6;
  const int lane16 = tid & 15;
  const int g4 = (tid >> 4) & 3;
  const int s0 = blockIdx.x * GSAMP;

  const float* lutf = (const float*)ws;            // 9 x LUT_STRIDE f32
  const unsigned short* Ww2t = ws + 65536;
  const unsigned short* Ww1p = ws + 131072;

  const int c0 = wave * 32 + lane16;       // wave's two output columns
  const int c1 = wave * 32 + 16 + lane16;

  // ---- lag-LUT: threads 0..143, one (sample, d) each ----
  if (tid < 144) {
    int samp = tid / 9, d = tid - samp * 9;
    float x = lags[(s0 + samp) * NLAGS + d];
    float tp = (x - SLO) * KINV;
    tp = fminf(fmaxf(tp, 0.0f), (float)(NK - 2) + 0.999f);
    int j = (int)tp; float fr = tp - (float)j;
    const float* row = lutf + d * LUT_STRIDE;
    float lo = row[j], hi = row[j + 1];
    scratch2[tid] = fmaf(fr, hi - lo, lo);   // samp*9 + d
  }

  // ---- Phase B: w0 = tanh(weather @ Ww1 + bw1) -> sT (K pad 8->32) ----
  {
    short8 bf0 = *(const short8*)(Ww1p + c0 * 32 + g4 * 8);
    short8 bf1 = *(const short8*)(Ww1p + c1 * 32 + g4 * 8);
    float bia0 = bw1[c0], bia1 = bw1[c1];
    #pragma unroll
    for (int m = 0; m < 9; ++m) {         // m = lag tile; row-in-tile = lane16
      S8 a8;
      if (g4 == 0) {
        const float* wp = weather + (size_t)(s0 + lane16) * 72 + m * 8;
        float4v x0 = *(const float4v*)(wp);
        float4v x1 = *(const float4v*)(wp + 4);
        a8.v = (short8){0,0,0,0,0,0,0,0};
        unsigned int p0 = pkbf16(x0[0], x0[1]), p1 = pkbf16(x0[2], x0[3]);
        unsigned int p2 = pkbf16(x1[0], x1[1]), p3 = pkbf16(x1[2], x1[3]);
        a8.u[0] = (unsigned short)p0; a8.u[1] = (unsigned short)(p0 >> 16);
        a8.u[2] = (unsigned short)p1; a8.u[3] = (unsigned short)(p1 >> 16);
        a8.u[4] = (unsigned short)p2; a8.u[5] = (unsigned short)(p2 >> 16);
        a8.u[6] = (unsigned short)p3; a8.u[7] = (unsigned short)(p3 >> 16);
      } else {
        a8.v = (short8){0,0,0,0,0,0,0,0};
      }
      float4v zz = {0.f, 0.f, 0.f, 0.f};
      float4v ac0 = mfma16(a8.v, bf0, zz);
      float4v ac1 = mfma16(a8.v, bf1, zz);
      #pragma unroll
      for (int i = 0; i < 4; ++i) {
        int row = m * 16 + g4 * 4 + i;    // C/D: col=lane&15, row=(lane>>4)*4+i
        unsigned int p = pkbf16(ftanh(ac0[i] + bia0), ftanh(ac1[i] + bia1));
        sT[tmE(row, c0)] = (unsigned short)p;
        sT[tmE(row, c1)] = (unsigned short)(p >> 16);
      }
    }
  }
  __syncthreads();   // B1: sT = w0 and scratch2 published

  float P[4] = {0.f, 0.f, 0.f, 0.f};   // per-lane partial outputs, samples g4*4+i

  // ---- gemm-sW (K=256): w1 = tanh(w0@Ww2+bw2); epilogue: P += <w1, Tw> ----
  {
    float4v acc0[9], acc1[9];
    #pragma unroll
    for (int m = 0; m < 9; ++m) {
      float4v z = {0.f,0.f,0.f,0.f};
      acc0[m] = z; acc1[m] = z;
    }
    #pragma unroll
    for (int kk = 0; kk < 8; ++kk) {
      short8 b0 = *(const short8*)(Ww2t + c0 * 256 + kk * 32 + g4 * 8);
      short8 b1 = *(const short8*)(Ww2t + c1 * 256 + kk * 32 + g4 * 8);
      #pragma unroll
      for (int m = 0; m < 9; ++m) {
        short8 a = *(const short8*)(sT + tmC(m * 16 + lane16, kk * 4 + g4));
        acc0[m] = mfma16(a, b0, acc0[m]);
        acc1[m] = mfma16(a, b1, acc1[m]);
      }
    }
    float twc0[9], twc1[9];
    #pragma unroll
    for (int m = 0; m < 9; ++m) {
      twc0[m] = vtab[2304 + m * 256 + c0];   // Tw[lag=m][col]
      twc1[m] = vtab[2304 + m * 256 + c1];
    }
    float bia0 = bw2[c0], bia1 = bw2[c1];
    #pragma unroll
    for (int m = 0; m < 9; ++m) {
      #pragma unroll
      for (int i = 0; i < 4; ++i) {
        float t0 = ftanh(acc0[m][i] + bia0);   // w1, f32 (never quantized)
        float t1 = ftanh(acc1[m][i] + bia1);
        P[i] = fmaf(t0, twc0[m], P[i]);
        P[i] = fmaf(t1, twc1[m], P[i]);
      }
    }
  }

  // ---- reduce: cols (shfl within lane16 groups) then waves (scratch) ----
  #pragma unroll
  for (int off = 8; off >= 1; off >>= 1) {
    #pragma unroll
    for (int i = 0; i < 4; ++i) P[i] += __shfl_down(P[i], off, 16);
  }
  if (lane16 == 0) {
    #pragma unroll
    for (int i = 0; i < 4; ++i) scratch[wave * 16 + g4 * 4 + i] = P[i];
  }
  __syncthreads();   // B2: scratch published
  if (tid < GSAMP) {
    float sum = 0.f;
    #pragma unroll
    for (int w = 0; w < 8; ++w) sum += scratch[w * 16 + tid];
    float lsum = 0.f;
    #pragma unroll
    for (int d = 0; d < 9; ++d) lsum += scratch2[tid * 9 + d];
    out[s0 + tid] = sum + lsum + vtab[4608];   // + C0'
  }
}

extern "C" void kernel_launch(void* const* d_in, const int* in_sizes, int n_in,
                              void* d_out, int out_size, void* d_ws, size_t ws_size,
                              hipStream_t stream) {
  const float* lags    = (const float*)d_in[0];
  const float* weather = (const float*)d_in[1];
  const float* Wl1     = (const float*)d_in[2];
  const float* bl1     = (const float*)d_in[3];
  const float* gbn     = (const float*)d_in[4];
  const float* bbn     = (const float*)d_in[5];
  const float* Wl2     = (const float*)d_in[6];
  const float* bl2     = (const float*)d_in[7];
  const float* Ww1     = (const float*)d_in[8];
  const float* bw1     = (const float*)d_in[9];
  const float* Ww2     = (const float*)d_in[10];
  const float* bw2     = (const float*)d_in[11];
  const float* Wm1     = (const float*)d_in[12];
  const float* bm1     = (const float*)d_in[13];
  const float* Wm2     = (const float*)d_in[14];
  const float* bm2     = (const float*)d_in[15];
  const float* Wreg    = (const float*)d_in[16];
  const float* breg    = (const float*)d_in[17];
  unsigned short* ws = (unsigned short*)d_ws;
  float* vtab = (float*)(ws + 139264);    // byte offset 278,528 (16B-aligned)
  float* lutf = (float*)ws;               // reuses dead Wl2t region (128KB)

  // prep_all: 144 staging blocks + 577 prep2a wave-blocks = 721
  prep_all<<<721, 512, 0, stream>>>(Ww2, Ww1, Wm2, Wreg, bm2, breg, ws, vtab);
  prep2b_kernel<<<577, 512, 0, stream>>>(Wm1, bm1, vtab);
  prep3_lut<<<1024, 256, 0, stream>>>(Wl1, bl1, gbn, bbn, Wl2, bl2, vtab, lutf);

  const int nblocks = 32768 / GSAMP;  // 2048
  fused_kernel<<<nblocks, NTHREADS, 0, stream>>>(
      lags, weather, bw1, bw2, ws, vtab, (float*)d_out);
}